// Round 7
// baseline (323.819 us; speedup 1.0000x reference)
//
#include <hip/hip_runtime.h>
#include <math.h>

#define BN 4096
#define DD 128
#define NCLS 64
#define NT 32                        // 128-row tiles per dim
#define NTILES (NT * (NT + 1) / 2)   // 528 upper-tri tiles
#define NBLK 256                     // persistent blocks; LDS 66KB -> capacity 2/CU -> 512 >= 256, residency guaranteed
#define NJB 32                       // nes partials per row

typedef __attribute__((ext_vector_type(8))) short short8;
typedef __attribute__((ext_vector_type(4))) float f32x4;

__device__ __forceinline__ unsigned short f2bf(float f) {
    unsigned int u = __float_as_uint(f);
    u += 0x7FFFu + ((u >> 16) & 1u);   // RNE; inputs are finite normals
    return (unsigned short)(u >> 16);
}

__device__ __forceinline__ void gload_lds16(const void* g, void* l) {
    __builtin_amdgcn_global_load_lds(
        (const __attribute__((address_space(1))) unsigned int*)g,
        (__attribute__((address_space(3))) unsigned int*)l, 16, 0, 0);
}

// software grid barrier: release-fence + device-scope arrival, acquire-spin,
// then block-wide fence (invalidates per-CU L1; handles cross-XCD L2).
__device__ __forceinline__ void grid_barrier(unsigned int* bar, int idx) {
    __syncthreads();
    if (threadIdx.x == 0) {
        __threadfence();
        atomicAdd(&bar[idx], 1u);
        while (__hip_atomic_load(&bar[idx], __ATOMIC_ACQUIRE, __HIP_MEMORY_SCOPE_AGENT) < NBLK)
            __builtin_amdgcn_s_sleep(2);
    }
    __syncthreads();
    __threadfence();
}

// ws layout:
//   bar[8] u32 | sbf[BN*DD] bf16 | mag[BN] f32 | nes_part[BN][NJB] f32 |
//   part_sum[NBLK] f32 | part_cnt[NBLK] u32 |
//   cls_cnt[64] | cls_start[64] | cls_list[BN]

__global__ __launch_bounds__(256)
void mega_kernel(const float* __restrict__ score, const int* __restrict__ target,
                 const float* __restrict__ alphap, float* __restrict__ out,
                 unsigned int* __restrict__ bar,
                 unsigned short* __restrict__ sbf, float* __restrict__ mag,
                 float* __restrict__ nes_part,
                 float* __restrict__ part_sum, unsigned int* __restrict__ part_cnt,
                 int* __restrict__ cls_cnt, int* __restrict__ cls_start,
                 int* __restrict__ cls_list) {
    __shared__ __align__(16) unsigned short lds[2 * 128 * 128];   // 64 KB
    __shared__ float rowsum[2][128];
    __shared__ float colsum[2][128];
    __shared__ float ssum[4];
    __shared__ unsigned int scnt[4];

    const int b   = blockIdx.x;
    const int tid = threadIdx.x;
    const int lane = tid & 63;
    const int lhi = lane >> 4, llo = lane & 15;
    const int w = tid >> 6;

    // ---- P0: bf16 cast + row norms (all blocks); bucketing (block NBLK-1) ----
    {
        #pragma unroll
        for (int it = 0; it < 4; ++it) {           // 1024 row-quads / 256 blocks
            int row = (b * 4 + it) * 4 + w;
            float2 v = *reinterpret_cast<const float2*>(score + (size_t)row * DD + lane * 2);
            float s = v.x * v.x + v.y * v.y;
            #pragma unroll
            for (int off = 32; off; off >>= 1) s += __shfl_xor(s, off);
            ushort2 u; u.x = f2bf(v.x); u.y = f2bf(v.y);
            *reinterpret_cast<ushort2*>(sbf + (size_t)row * DD + lane * 2) = u;
            if (lane == 0) mag[row] = s;
        }
        if (b == NBLK - 1) {
            int* hist = reinterpret_cast<int*>(lds);
            int* offs = hist + NCLS;
            if (tid < NCLS) hist[tid] = 0;
            __syncthreads();
            for (int i = tid; i < BN; i += 256) atomicAdd(&hist[target[i]], 1);
            __syncthreads();
            if (tid == 0) {
                int run = 0;
                for (int c = 0; c < NCLS; ++c) {
                    cls_cnt[c] = hist[c];
                    cls_start[c] = run;
                    offs[c] = run;
                    run += hist[c];
                }
            }
            __syncthreads();
            for (int i = tid; i < BN; i += 256) {
                int p = atomicAdd(&offs[target[i]], 1);
                cls_list[p] = i;
            }
        }
    }
    grid_barrier(bar, 0);

    // ---- P1: nes tiles (upper triangle incl. diagonal), bf16 MFMA ----
    {
        const float alpha = alphap[0];
        const int wr = w >> 1, wc = w & 1;
        bool first = true;
        for (int t = b; t < NTILES; t += NBLK) {
            int ib = 0, rem = t;
            while (rem >= NT - ib) { rem -= NT - ib; ib++; }
            int jb = ib + rem;
            const int i0 = ib * 128, j0 = jb * 128;
            const bool diag = (ib == jb);

            if (!first) __syncthreads();   // protect lds + rowsum/colsum reuse
            first = false;
            #pragma unroll
            for (int tt = 0; tt < 8; ++tt) {
                int rl = w * 32 + tt * 4 + lhi;
                int ch = llo ^ (rl & 7);                  // pre-swizzled source chunk (rule 21)
                gload_lds16(sbf + (size_t)(i0 + rl) * DD + ch * 8,
                            lds + (w * 32 + tt * 4) * 128);
                if (!diag)
                    gload_lds16(sbf + (size_t)(j0 + rl) * DD + ch * 8,
                                lds + 128 * 128 + (w * 32 + tt * 4) * 128);
            }
            __syncthreads();

            const unsigned short* bbase = diag ? lds : (lds + 128 * 128);
            f32x4 acc[4][4] = {};
            #pragma unroll
            for (int kk = 0; kk < 4; ++kk) {
                short8 a[4], bb[4];
                #pragma unroll
                for (int m = 0; m < 4; ++m) {
                    int r = wr * 64 + m * 16 + llo;
                    int ch = (kk * 4 + lhi) ^ (r & 7);
                    a[m] = *reinterpret_cast<const short8*>(lds + r * 128 + ch * 8);
                }
                #pragma unroll
                for (int n = 0; n < 4; ++n) {
                    int r = wc * 64 + n * 16 + llo;
                    int ch = (kk * 4 + lhi) ^ (r & 7);
                    bb[n] = *reinterpret_cast<const short8*>(bbase + r * 128 + ch * 8);
                }
                #pragma unroll
                for (int m = 0; m < 4; ++m)
                    #pragma unroll
                    for (int n = 0; n < 4; ++n)
                        acc[m][n] = __builtin_amdgcn_mfma_f32_16x16x32_bf16(a[m], bb[n], acc[m][n], 0, 0, 0);
            }

            float mj[4]; int tj[4];
            #pragma unroll
            for (int n = 0; n < 4; ++n) {
                int j = j0 + wc * 64 + n * 16 + llo;
                mj[n] = mag[j]; tj[n] = target[j];
            }
            float cs[4] = {0.f, 0.f, 0.f, 0.f};
            #pragma unroll
            for (int m = 0; m < 4; ++m) {
                #pragma unroll
                for (int rg = 0; rg < 4; ++rg) {
                    int li = wr * 64 + m * 16 + lhi * 4 + rg;
                    int i = i0 + li;
                    float mi = mag[i];
                    int ti = target[i];
                    float rs = 0.f;
                    #pragma unroll
                    for (int n = 0; n < 4; ++n) {
                        float d2 = fmaxf(mi + mj[n] - 2.0f * acc[m][n][rg], 0.0f);
                        float dist = sqrtf(d2);
                        float e = (ti != tj[n]) ? __expf(alpha - dist) : 0.0f;
                        rs += e;
                        cs[n] += e;
                    }
                    rs += __shfl_xor(rs, 1);
                    rs += __shfl_xor(rs, 2);
                    rs += __shfl_xor(rs, 4);
                    rs += __shfl_xor(rs, 8);
                    if (llo == 0) rowsum[wc][li] = rs;
                }
            }
            #pragma unroll
            for (int n = 0; n < 4; ++n) {
                cs[n] += __shfl_xor(cs[n], 16);
                cs[n] += __shfl_xor(cs[n], 32);
                if (lhi == 0) colsum[wr][wc * 64 + n * 16 + llo] = cs[n];
            }
            __syncthreads();
            if (tid < 128) {
                nes_part[(size_t)(i0 + tid) * NJB + jb] = rowsum[0][tid] + rowsum[1][tid];
                if (!diag)
                    nes_part[(size_t)(j0 + tid) * NJB + ib] = colsum[0][tid] + colsum[1][tid];
            }
        }
    }
    grid_barrier(bar, 1);

    // ---- P2: positive pairs (class-bucketed, 16-lane group per pair) ----
    {
        const int c  = b & 63;          // class
        const int sp = b >> 6;          // split 0..3
        const int n = cls_cnt[c], s0 = cls_start[c];
        const int grp = tid >> 4;
        const int g0 = sp * 16 + grp;   // 64 groups per class
        const int nG = 64;
        const int nn = n * n;
        float s = 0.f;
        unsigned int cc = 0;
        for (int p = g0; p < nn; p += nG) {
            int a = p / n, bq = p - a * n;
            if (bq <= a) continue;
            int i = cls_list[s0 + a], j = cls_list[s0 + bq];
            const float4* ra = reinterpret_cast<const float4*>(score + (size_t)i * DD) + llo * 2;
            const float4* rb = reinterpret_cast<const float4*>(score + (size_t)j * DD) + llo * 2;
            float4 x0 = ra[0], x1 = ra[1];
            float4 y0 = rb[0], y1 = rb[1];
            float dx, d2 = 0.f;
            dx = x0.x - y0.x; d2 += dx * dx;
            dx = x0.y - y0.y; d2 += dx * dx;
            dx = x0.z - y0.z; d2 += dx * dx;
            dx = x0.w - y0.w; d2 += dx * dx;
            dx = x1.x - y1.x; d2 += dx * dx;
            dx = x1.y - y1.y; d2 += dx * dx;
            dx = x1.z - y1.z; d2 += dx * dx;
            dx = x1.w - y1.w; d2 += dx * dx;
            float2 pi = *reinterpret_cast<const float2*>(nes_part + (size_t)i * NJB + llo * 2);
            float2 pj = *reinterpret_cast<const float2*>(nes_part + (size_t)j * NJB + llo * 2);
            float ni = pi.x + pi.y;
            float nj = pj.x + pj.y;
            #pragma unroll
            for (int off = 1; off < 16; off <<= 1) {
                d2 += __shfl_xor(d2, off);
                ni += __shfl_xor(ni, off);
                nj += __shfl_xor(nj, off);
            }
            if (llo == 0) {
                float dist = sqrtf(d2);
                float tv = __logf(ni + nj) + dist;
                if (tv > 0.f) s += tv * tv;
                cc++;
            }
        }
        #pragma unroll
        for (int off = 1; off < 64; off <<= 1) {
            s += __shfl_xor(s, off);
            cc += __shfl_xor(cc, off);
        }
        __syncthreads();   // lds/ssum reuse safety
        if ((tid & 63) == 0) { ssum[w] = s; scnt[w] = cc; }
        __syncthreads();
        if (tid == 0) {
            part_sum[b] = ssum[0] + ssum[1] + ssum[2] + ssum[3];
            part_cnt[b] = scnt[0] + scnt[1] + scnt[2] + scnt[3];
        }
    }
    grid_barrier(bar, 2);

    // ---- P3: finalize (block 0) ----
    if (b == 0) {
        float s = part_sum[tid];
        unsigned int c = part_cnt[tid];
        #pragma unroll
        for (int off = 1; off < 64; off <<= 1) {
            s += __shfl_xor(s, off);
            c += __shfl_xor(c, off);
        }
        __syncthreads();
        if ((tid & 63) == 0) { ssum[w] = s; scnt[w] = c; }
        __syncthreads();
        if (tid == 0) {
            float S = ssum[0] + ssum[1] + ssum[2] + ssum[3];
            float C = (float)(scnt[0] + scnt[1] + scnt[2] + scnt[3]);
            out[0] = S / (2.0f * C);
        }
    }
}

extern "C" void kernel_launch(void* const* d_in, const int* in_sizes, int n_in,
                              void* d_out, int out_size, void* d_ws, size_t ws_size,
                              hipStream_t stream) {
    const float* score  = (const float*)d_in[0];
    const int*   target = (const int*)d_in[1];
    const float* alpha  = (const float*)d_in[2];
    float* out = (float*)d_out;

    unsigned int* bar = (unsigned int*)d_ws;
    unsigned short* sbf = (unsigned short*)(bar + 8);
    float* mag      = (float*)((char*)sbf + (size_t)BN * DD * 2);
    float* nes_part = mag + BN;
    float* part_sum = nes_part + (size_t)BN * NJB;
    unsigned int* part_cnt = (unsigned int*)(part_sum + NBLK);
    int* cls_cnt   = (int*)(part_cnt + NBLK);
    int* cls_start = cls_cnt + NCLS;
    int* cls_list  = cls_start + NCLS;

    hipMemsetAsync(bar, 0, 8 * sizeof(unsigned int), stream);
    mega_kernel<<<NBLK, 256, 0, stream>>>(score, target, alpha, out,
                                          bar, sbf, mag, nes_part,
                                          part_sum, part_cnt,
                                          cls_cnt, cls_start, cls_list);
}

// Round 9
// 103.059 us; speedup vs baseline: 3.1421x; 3.1421x over previous
//
#include <hip/hip_runtime.h>
#include <math.h>

#define BN 4096
#define DD 128
#define NCLS 64
#define NT 32                    // 128-row tiles per dim
#define NTILE2 (NT * NT)         // 1024 tile slots (upper-tri used)
#define NJB 32                   // nes partials per row
#define SLOTS 2048               // per-tile record slots (expect ~256)
#define OVCAP (8u * 1024u * 1024u)

typedef __attribute__((ext_vector_type(8))) short short8;
typedef __attribute__((ext_vector_type(4))) float f32x4;

__device__ __forceinline__ unsigned short f2bf(float f) {
    unsigned int u = __float_as_uint(f);
    u += 0x7FFFu + ((u >> 16) & 1u);   // RNE; inputs are finite normals
    return (unsigned short)(u >> 16);
}

__device__ __forceinline__ void gload_lds16(const void* g, void* l) {
    __builtin_amdgcn_global_load_lds(
        (const __attribute__((address_space(1))) unsigned int*)g,
        (__attribute__((address_space(3))) unsigned int*)l, 16, 0, 0);
}

// ws layout (bytes, 8-aligned):
//   sbf[BN*DD] bf16 | mag[BN] f32 | nes_part[NJB][BN] f32 | nes[BN] f32 |
//   part_sum[1024] f32 | part_cnt[1024] u32 | tilecnt[1024] i32 |
//   ovcnt u32 (+pad to 16 words) | recs[NTILE2*SLOTS] uint2 | ovrecs[OVCAP] uint2

__global__ __launch_bounds__(256)
void prep_kernel(const float* __restrict__ score, unsigned short* __restrict__ sbf,
                 float* __restrict__ mag) {
    int row  = blockIdx.x * 4 + (threadIdx.x >> 6);
    int lane = threadIdx.x & 63;
    float2 v = *reinterpret_cast<const float2*>(score + (size_t)row * DD + lane * 2);
    float s = v.x * v.x + v.y * v.y;
    #pragma unroll
    for (int off = 32; off; off >>= 1) s += __shfl_xor(s, off);
    ushort2 u; u.x = f2bf(v.x); u.y = f2bf(v.y);
    *reinterpret_cast<ushort2*>(sbf + (size_t)row * DD + lane * 2) = u;
    if (lane == 0) mag[row] = s;
}

// Upper-triangle 128x128 tiles (jb >= ib); off-diagonal tiles emit both row-
// and col-sums of exp(alpha-dist) (masked), PLUS compact records for the
// positive pairs (ti==tj, j>i) so the pos pass never recomputes distances.
// LDS content chunk-swizzled via pre-swizzled global_load_lds source (rule 21).
__global__ __launch_bounds__(256)
void nes_kernel(const unsigned short* __restrict__ sbf, const int* __restrict__ target,
                const float* __restrict__ alphap, const float* __restrict__ mag,
                float* __restrict__ nes_part,
                uint2* __restrict__ recs, uint2* __restrict__ ovrecs,
                int* __restrict__ tilecnt, unsigned int* __restrict__ ovcnt) {
    const int ib = blockIdx.x, jb = blockIdx.y;
    const int tile = ib * NT + jb;
    if (jb < ib) {
        if (threadIdx.x == 0) tilecnt[tile] = 0;
        return;
    }
    __shared__ __align__(16) unsigned short lds[2 * 128 * 128];   // A | B, 64 KB
    __shared__ float rowsum[2][128];
    __shared__ float colsum[2][128];
    __shared__ int lcnt;
    const int tid = threadIdx.x;
    const int w = tid >> 6, lane = tid & 63;
    const int lhi = lane >> 4, llo = lane & 15;
    const int i0 = ib * 128, j0 = jb * 128;
    const bool diag = (ib == jb);

    if (tid == 0) lcnt = 0;
    #pragma unroll
    for (int t = 0; t < 8; ++t) {
        int rl = w * 32 + t * 4 + lhi;
        int ch = llo ^ (rl & 7);                  // pre-swizzled source chunk
        gload_lds16(sbf + (size_t)(i0 + rl) * DD + ch * 8, lds + (w * 32 + t * 4) * 128);
        if (!diag)
            gload_lds16(sbf + (size_t)(j0 + rl) * DD + ch * 8,
                        lds + 128 * 128 + (w * 32 + t * 4) * 128);
    }
    __syncthreads();

    const unsigned short* bbase = diag ? lds : (lds + 128 * 128);
    const int wr = w >> 1, wc = w & 1;
    f32x4 acc[4][4] = {};
    #pragma unroll
    for (int kk = 0; kk < 4; ++kk) {
        short8 a[4], b[4];
        #pragma unroll
        for (int m = 0; m < 4; ++m) {
            int r = wr * 64 + m * 16 + llo;
            int ch = (kk * 4 + lhi) ^ (r & 7);
            a[m] = *reinterpret_cast<const short8*>(lds + r * 128 + ch * 8);
        }
        #pragma unroll
        for (int n = 0; n < 4; ++n) {
            int r = wc * 64 + n * 16 + llo;
            int ch = (kk * 4 + lhi) ^ (r & 7);
            b[n] = *reinterpret_cast<const short8*>(bbase + r * 128 + ch * 8);
        }
        #pragma unroll
        for (int m = 0; m < 4; ++m)
            #pragma unroll
            for (int n = 0; n < 4; ++n)
                acc[m][n] = __builtin_amdgcn_mfma_f32_16x16x32_bf16(a[m], b[n], acc[m][n], 0, 0, 0);
    }

    // epilogue (C/D: col = lane&15, row = lhi*4+reg)
    const float alpha = alphap[0];
    float mj[4]; int tj[4]; int jj[4];
    #pragma unroll
    for (int n = 0; n < 4; ++n) {
        int j = j0 + wc * 64 + n * 16 + llo;
        jj[n] = j; mj[n] = mag[j]; tj[n] = target[j];
    }
    float cs[4] = {0.f, 0.f, 0.f, 0.f};
    #pragma unroll
    for (int m = 0; m < 4; ++m) {
        #pragma unroll
        for (int rg = 0; rg < 4; ++rg) {
            int li = wr * 64 + m * 16 + lhi * 4 + rg;
            int i = i0 + li;
            float mi = mag[i];
            int ti = target[i];
            float rs = 0.f;
            #pragma unroll
            for (int n = 0; n < 4; ++n) {
                float d2 = fmaxf(mi + mj[n] - 2.0f * acc[m][n][rg], 0.0f);
                float dist = sqrtf(d2);
                bool p = (ti == tj[n]);
                float e = p ? 0.0f : __expf(alpha - dist);
                rs += e;
                cs[n] += e;
                if (p && jj[n] > i) {
                    int slot = atomicAdd(&lcnt, 1);
                    uint2 r;
                    r.x = __float_as_uint(dist);
                    r.y = ((unsigned)i << 16) | (unsigned)jj[n];
                    if (slot < SLOTS) recs[(size_t)tile * SLOTS + slot] = r;
                    else {
                        unsigned o = atomicAdd(ovcnt, 1u);
                        if (o < OVCAP) ovrecs[o] = r;
                    }
                }
            }
            rs += __shfl_xor(rs, 1);
            rs += __shfl_xor(rs, 2);
            rs += __shfl_xor(rs, 4);
            rs += __shfl_xor(rs, 8);
            if (llo == 0) rowsum[wc][li] = rs;
        }
    }
    #pragma unroll
    for (int n = 0; n < 4; ++n) {
        cs[n] += __shfl_xor(cs[n], 16);
        cs[n] += __shfl_xor(cs[n], 32);
        if (lhi == 0) colsum[wr][wc * 64 + n * 16 + llo] = cs[n];
    }
    __syncthreads();
    // col-major partials [k][i] for a coalesced reduce
    if (tid < 128) {
        nes_part[(size_t)jb * BN + i0 + tid] = rowsum[0][tid] + rowsum[1][tid];
        if (!diag)
            nes_part[(size_t)ib * BN + j0 + tid] = colsum[0][tid] + colsum[1][tid];
    }
    if (tid == 0) tilecnt[tile] = lcnt;
}

__global__ __launch_bounds__(256)
void nes_reduce_kernel(const float* __restrict__ nes_part, float* __restrict__ nes) {
    int t = blockIdx.x * 256 + threadIdx.x;   // 0..BN-1
    float s = 0.f;
    #pragma unroll
    for (int k = 0; k < NJB; ++k) s += nes_part[(size_t)k * BN + t];
    nes[t] = s;
}

// map over emitted records: log(nes_i + nes_j) + dist -> relu -> square.
__global__ __launch_bounds__(256)
void pos_kernel(const uint2* __restrict__ recs, const uint2* __restrict__ ovrecs,
                const int* __restrict__ tilecnt, const unsigned int* __restrict__ ovcnt,
                const float* __restrict__ nes,
                float* __restrict__ part_sum, unsigned int* __restrict__ part_cnt) {
    __shared__ float ssum[4];
    __shared__ unsigned int scnt[4];
    const int t = blockIdx.x;
    const int tid = threadIdx.x;
    const int w = tid >> 6;
    int cnt = tilecnt[t];
    if (cnt > SLOTS) cnt = SLOTS;
    float s = 0.f;
    unsigned int cc = 0;
    for (int k = tid; k < cnt; k += 256) {
        uint2 r = recs[(size_t)t * SLOTS + k];
        float dist = __uint_as_float(r.x);
        int i = r.y >> 16, j = r.y & 0xFFFF;
        float tv = __logf(nes[i] + nes[j]) + dist;
        if (tv > 0.f) s += tv * tv;
        cc++;
    }
    unsigned int oc = *ovcnt;
    if (oc > OVCAP) oc = OVCAP;
    for (unsigned int k = (unsigned)t * 256u + tid; k < oc; k += NTILE2 * 256u) {
        uint2 r = ovrecs[k];
        float dist = __uint_as_float(r.x);
        int i = r.y >> 16, j = r.y & 0xFFFF;
        float tv = __logf(nes[i] + nes[j]) + dist;
        if (tv > 0.f) s += tv * tv;
        cc++;
    }
    #pragma unroll
    for (int off = 1; off < 64; off <<= 1) {
        s += __shfl_xor(s, off);
        cc += __shfl_xor(cc, off);
    }
    if ((tid & 63) == 0) { ssum[w] = s; scnt[w] = cc; }
    __syncthreads();
    if (tid == 0) {
        part_sum[t] = ssum[0] + ssum[1] + ssum[2] + ssum[3];
        part_cnt[t] = scnt[0] + scnt[1] + scnt[2] + scnt[3];
    }
}

__global__ __launch_bounds__(256)
void finalize_kernel(const float* __restrict__ part_sum,
                     const unsigned int* __restrict__ part_cnt,
                     float* __restrict__ out) {
    __shared__ float fs[4];
    __shared__ unsigned int fc[4];
    int tid = threadIdx.x;
    float s = 0.f;
    unsigned int c = 0;
    #pragma unroll
    for (int k = 0; k < NTILE2 / 256; ++k) {
        s += part_sum[k * 256 + tid];
        c += part_cnt[k * 256 + tid];
    }
    #pragma unroll
    for (int off = 1; off < 64; off <<= 1) {
        s += __shfl_xor(s, off);
        c += __shfl_xor(c, off);
    }
    if ((tid & 63) == 0) { fs[tid >> 6] = s; fc[tid >> 6] = c; }
    __syncthreads();
    if (tid == 0) {
        float S = fs[0] + fs[1] + fs[2] + fs[3];
        float C = (float)(fc[0] + fc[1] + fc[2] + fc[3]);
        out[0] = S / (2.0f * C);
    }
}

extern "C" void kernel_launch(void* const* d_in, const int* in_sizes, int n_in,
                              void* d_out, int out_size, void* d_ws, size_t ws_size,
                              hipStream_t stream) {
    const float* score  = (const float*)d_in[0];
    const int*   target = (const int*)d_in[1];
    const float* alpha  = (const float*)d_in[2];
    float* out = (float*)d_out;

    unsigned short* sbf = (unsigned short*)d_ws;
    float* mag      = (float*)((char*)d_ws + (size_t)BN * DD * 2);
    float* nes_part = mag + BN;
    float* nes      = nes_part + (size_t)NJB * BN;
    float* part_sum = nes + BN;
    unsigned int* part_cnt = (unsigned int*)(part_sum + NTILE2);
    int* tilecnt    = (int*)(part_cnt + NTILE2);
    unsigned int* ovcnt = (unsigned int*)(tilecnt + NTILE2);
    uint2* recs     = (uint2*)(ovcnt + 16);
    uint2* ovrecs   = recs + (size_t)NTILE2 * SLOTS;

    hipMemsetAsync(ovcnt, 0, sizeof(unsigned int), stream);

    prep_kernel<<<BN / 4, 256, 0, stream>>>(score, sbf, mag);
    dim3 g(NT, NT);
    nes_kernel<<<g, 256, 0, stream>>>(sbf, target, alpha, mag, nes_part,
                                      recs, ovrecs, tilecnt, ovcnt);
    nes_reduce_kernel<<<BN / 256, 256, 0, stream>>>(nes_part, nes);
    pos_kernel<<<NTILE2, 256, 0, stream>>>(recs, ovrecs, tilecnt, ovcnt, nes,
                                           part_sum, part_cnt);
    finalize_kernel<<<1, 256, 0, stream>>>(part_sum, part_cnt, out);
}